// Round 7
// baseline (144.423 us; speedup 1.0000x reference)
//
#include <hip/hip_runtime.h>
#include <hip/hip_fp16.h>

// Problem constants
#define OOv   200
#define KKv   1600
#define OTILES 7               // col-tiles of 32 (224 padded)
#define TSTEPS 100             // K=16 MFMA steps
#define NMG   20               // macro-groups = super-steps (5 steps each)
#define STEP_BYTES 7168        // 224 cols * 16 k * 2 B
#define SUPER_BYTES 35840      // 5 steps

typedef _Float16 half8  __attribute__((ext_vector_type(8)));
typedef _Float16 half2v __attribute__((ext_vector_type(2)));
typedef __attribute__((ext_vector_type(4)))  float floatx4;
typedef __attribute__((ext_vector_type(16))) float floatx16;

// ---------------------------------------------------------------------------
// Pre-kernel: W [200][1600] fp32 -> Wh fp16 for 32x32x16 MFMA, K-permuted.
// half-index: idx = t*3584 + (o*2 + h)*8 + j   (t=0..99, o=0..223, h=0..1)
// k_orig = (2*(t/5) + h)*40 + 8*(t%5) + j
// => at step t, y-window m in [8*(t%5), +8) uniform; x-index n = 2*(t/5)+h.
// ---------------------------------------------------------------------------
__global__ void wb_convert_kernel(const float* __restrict__ W,
                                  unsigned short* __restrict__ Wh) {
    int idx = blockIdx.x * 256 + threadIdx.x;
    if (idx >= TSTEPS * 224 * 16) return;        // 358400
    int j    = idx & 7;
    int slot = (idx >> 3) % 448;
    int t    = (idx >> 3) / 448;
    int o    = slot >> 1;
    int h    = slot & 1;
    int k    = (2 * (t / 5) + h) * 40 + 8 * (t % 5) + j;
    float v  = (o < OOv) ? W[o * KKv + k] : 0.0f;
    union { _Float16 h; unsigned short u; } cv; cv.h = (_Float16)v;
    Wh[idx] = cv.u;
}

// ---------------------------------------------------------------------------
// Main kernel: 512 blocks x 512 thr. Block = 128 rows x 224 cols.
// Waves: rowhalf = wave&1 (rt=2 tiles of 32), colgrp = wave>>1 ({2,2,2,1}).
// mfma_f32_32x32x16_f16: A[m= lane&31][k=8*(lane>>5)+j], B[k][n=lane&31];
// C/D: col=lane&31, row=(reg&3)+8*(reg>>2)+4*(lane>>5)   [m74/m101].
// y entirely in registers (2 rows x 20 regs); x scalar global loads (L1-hot);
// LDS = W double buffer ONLY. 20 barriers.
// ---------------------------------------------------------------------------
__global__ __launch_bounds__(512, 4) void cin_mfma_kernel(
        const float* __restrict__ X, const float* __restrict__ Y,
        const unsigned short* __restrict__ Wh, float* __restrict__ Out) {
    __shared__ __align__(16) unsigned char bsm[2 * SUPER_BYTES];   // 71680

    const int tid     = threadIdx.x;
    const int wave    = tid >> 6;
    const int lane    = tid & 63;
    const int c32     = lane & 31;
    const int h       = lane >> 5;
    const int rowhalf = wave & 1;
    const int colgrp  = wave >> 1;
    const int nt      = (colgrp == 3) ? 1 : 2;
    const int cbt     = colgrp * 2;
    const long blockbase = (long)blockIdx.x * 128;

    const long row0 = blockbase + rowhalf * 64 + c32;   // rt=0 row
    const long row1 = row0 + 32;                        // rt=1 row

    // ---- stage super-chunk 0 (35 KB over 8 waves)
    for (int u = wave; u < 35; u += 8) {
        int off = u * 1024 + lane * 16;
        __builtin_amdgcn_global_load_lds(
            (const __attribute__((address_space(1))) unsigned int*)((const char*)Wh + off),
            (__attribute__((address_space(3))) unsigned int*)(bsm + off),
            16, 0, 0);
    }

    // ---- y rows into registers (half2-packed): yr[r][p][q] = y[row_r][8p+2q..+2]
    half2v yr[2][5][4];
#pragma unroll
    for (int r = 0; r < 2; ++r) {
        const float* yp = Y + (r ? row1 : row0) * 40;
#pragma unroll
        for (int p = 0; p < 5; ++p) {
            floatx4 a = *(const floatx4*)(yp + p * 8);
            floatx4 b = *(const floatx4*)(yp + p * 8 + 4);
            yr[r][p][0] = (half2v){(_Float16)a.x, (_Float16)a.y};
            yr[r][p][1] = (half2v){(_Float16)a.z, (_Float16)a.w};
            yr[r][p][2] = (half2v){(_Float16)b.x, (_Float16)b.y};
            yr[r][p][3] = (half2v){(_Float16)b.z, (_Float16)b.w};
        }
    }
    // x prefetch for mg=0: n = h
    float xf0 = X[row0 * 40 + h];
    float xf1 = X[row1 * 40 + h];

    __syncthreads();

    floatx16 acc[2][2];
#pragma unroll
    for (int rt = 0; rt < 2; ++rt)
#pragma unroll
        for (int ct = 0; ct < 2; ++ct)
            acc[rt][ct] = (floatx16)0.f;

    const int bfoff = (c32 * 2 + h) * 16;   // per-lane byte offset in a step-chunk

    for (int mg = 0; mg < NMG; ++mg) {
        // x for this macro-group (prefetched), as broadcast half2
        half2v xs0 = (half2v){(_Float16)xf0, (_Float16)xf0};
        half2v xs1 = (half2v){(_Float16)xf1, (_Float16)xf1};
        if (mg + 1 < NMG) {
            xf0 = X[row0 * 40 + 2 * (mg + 1) + h];
            xf1 = X[row1 * 40 + 2 * (mg + 1) + h];
        }
        // stage next super-chunk (full super-step of latency cover)
        if (mg + 1 < NMG) {
            const char* src = (const char*)Wh + (size_t)(mg + 1) * SUPER_BYTES;
            unsigned char* dst = bsm + ((mg + 1) & 1) * SUPER_BYTES;
            for (int u = wave; u < 35; u += 8) {
                int off = u * 1024 + lane * 16;
                __builtin_amdgcn_global_load_lds(
                    (const __attribute__((address_space(1))) unsigned int*)(src + off),
                    (__attribute__((address_space(3))) unsigned int*)(dst + off),
                    16, 0, 0);
            }
        }
        const unsigned char* cbuf = bsm + (mg & 1) * SUPER_BYTES;

#pragma unroll
        for (int p = 0; p < 5; ++p) {
            const unsigned char* chunk = cbuf + p * STEP_BYTES;

            // B fragments first (b128 each), then A per-rt consumed immediately
            half8 bf[2];
#pragma unroll
            for (int ct = 0; ct < 2; ++ct)
                if (ct < nt)
                    bf[ct] = *(const half8*)(chunk + (cbt + ct) * 1024 + bfoff);

            union { half8 v8; half2v h2[4]; } af;
#pragma unroll
            for (int q = 0; q < 4; ++q) af.h2[q] = xs0 * yr[0][p][q];
            acc[0][0] = __builtin_amdgcn_mfma_f32_32x32x16_f16(af.v8, bf[0], acc[0][0], 0, 0, 0);
            if (nt > 1)
                acc[0][1] = __builtin_amdgcn_mfma_f32_32x32x16_f16(af.v8, bf[1], acc[0][1], 0, 0, 0);
#pragma unroll
            for (int q = 0; q < 4; ++q) af.h2[q] = xs1 * yr[1][p][q];
            acc[1][0] = __builtin_amdgcn_mfma_f32_32x32x16_f16(af.v8, bf[0], acc[1][0], 0, 0, 0);
            if (nt > 1)
                acc[1][1] = __builtin_amdgcn_mfma_f32_32x32x16_f16(af.v8, bf[1], acc[1][1], 0, 0, 0);
        }
        __syncthreads();   // one drain per super-step (20 total)
    }

    // ---- epilogue: C/D col = lane&31, row = (reg&3) + 8*(reg>>2) + 4*h [m74]
#pragma unroll
    for (int rt = 0; rt < 2; ++rt) {
#pragma unroll
        for (int ct = 0; ct < 2; ++ct) {
            if (ct >= nt) continue;
            int gcol = (cbt + ct) * 32 + c32;
            if (gcol < OOv) {
#pragma unroll
                for (int reg = 0; reg < 16; ++reg) {
                    long grow = blockbase + rowhalf * 64 + rt * 32
                              + (reg & 3) + 8 * (reg >> 2) + 4 * h;
                    Out[grow * OOv + gcol] = acc[rt][ct][reg];
                }
            }
        }
    }
}

extern "C" void kernel_launch(void* const* d_in, const int* in_sizes, int n_in,
                              void* d_out, int out_size, void* d_ws, size_t ws_size,
                              hipStream_t stream) {
    (void)in_sizes; (void)n_in; (void)out_size; (void)ws_size;
    const float* X = (const float*)d_in[0];
    const float* Y = (const float*)d_in[1];
    const float* W = (const float*)d_in[2];
    float* Out = (float*)d_out;
    unsigned short* Wh = (unsigned short*)d_ws;   // 716,800 B scratch

    wb_convert_kernel<<<1400, 256, 0, stream>>>(W, Wh);
    cin_mfma_kernel<<<512, 512, 0, stream>>>(X, Y, Wh, Out);
}